// Round 3
// baseline (2218.513 us; speedup 1.0000x reference)
//
#include <hip/hip_runtime.h>
#include <cstdint>
#include <cstring>

typedef _Float16 f16;
typedef _Float16 f16x8 __attribute__((ext_vector_type(8)));
typedef float f32x4 __attribute__((ext_vector_type(4)));

// ---- JAX threefry scheme: 1 = partitionable (jax >= 0.4.36 default), 0 = original
static constexpr int kPartitionable = 1;

struct Ptr8 { const float* p[8]; };
struct Keys8 { uint32_t k[8][2]; };

// ---------------- Threefry-2x32 (host + device) ----------------
__host__ __device__ inline void tf2x32(uint32_t k0, uint32_t k1,
                                       uint32_t x0, uint32_t x1,
                                       uint32_t& o0, uint32_t& o1) {
  uint32_t ks[3] = {k0, k1, k0 ^ k1 ^ 0x1BD11BDAu};
  uint32_t v0 = x0 + ks[0], v1 = x1 + ks[1];
  const int r0[4] = {13, 15, 26, 6};
  const int r1[4] = {17, 29, 16, 24};
  for (int g = 0; g < 5; ++g) {
    const int* rr = (g & 1) ? r1 : r0;
    for (int j = 0; j < 4; ++j) {
      v0 += v1;
      v1 = (v1 << rr[j]) | (v1 >> (32 - rr[j]));
      v1 ^= v0;
    }
    v0 += ks[(g + 1) % 3];
    v1 += ks[(g + 2) % 3] + (uint32_t)(g + 1);
  }
  o0 = v0; o1 = v1;
}

// ---------------- split-fp16 MFMA GEMM (encoder/LSTM path) ----------------
// C[m][n] = sum_k A[m][k]*Bt[n][k], A/Bt given as (hi,lo) fp16 pairs.
// 3 MFMAs per fragment pair: hi*hi + hi*lo + lo*hi (fp32 accumulate).
// LDS row stride padded 64->72 f16: fragment-read 2-way bank aliasing (free).
template <int BM, int BN>
__global__ __launch_bounds__(256, 2) void gemm_split(
    const f16* __restrict__ Ah, const f16* __restrict__ Al, int lda,
    const f16* __restrict__ Bh, const f16* __restrict__ Bl, int ldb,
    int K,
    const float* __restrict__ bias1, const float* __restrict__ bias2,
    int nReal, int relu, int writeF32,
    float* __restrict__ outF, f16* __restrict__ outH, f16* __restrict__ outL,
    int ldo) {
  constexpr int BK = 64;
  constexpr int BKP = BK + 8;  // 144 B stride, keeps 16B alignment
  constexpr int TM = BM / 32;
  constexpr int TN = BN / 32;
  static_assert(BM == BN, "square tiles only");
  __shared__ f16 sAh[BM * BKP];
  __shared__ f16 sAl[BM * BKP];
  __shared__ f16 sBh[BN * BKP];
  __shared__ f16 sBl[BN * BKP];

  const int tid = threadIdx.x;
  const int wave = tid >> 6;
  const int lane = tid & 63;
  const int wm = wave & 1, wn = wave >> 1;
  const int m0 = blockIdx.x * BM;
  const int n0 = blockIdx.y * BN;

  f32x4 acc[TM][TN];
  const f32x4 zero = {0.f, 0.f, 0.f, 0.f};
#pragma unroll
  for (int i = 0; i < TM; ++i)
#pragma unroll
    for (int j = 0; j < TN; ++j) acc[i][j] = zero;

  const f16* src;
  f16* dst;
  int ld, base;
  if (wave == 0)      { src = Ah; dst = sAh; ld = lda; base = m0; }
  else if (wave == 1) { src = Al; dst = sAl; ld = lda; base = m0; }
  else if (wave == 2) { src = Bh; dst = sBh; ld = ldb; base = n0; }
  else                { src = Bl; dst = sBl; ld = ldb; base = n0; }
  constexpr int NITER = (BM * 8) / 64;

  for (int k0 = 0; k0 < K; k0 += BK) {
    __syncthreads();
#pragma unroll
    for (int j = 0; j < NITER; ++j) {
      int c = j * 64 + lane;
      int row = c >> 3, col = c & 7;
      const uint4* g = (const uint4*)(src + (size_t)(base + row) * ld + k0) + col;
      uint4 v = *g;
      ((uint4*)dst)[row * 9 + col] = v;
    }
    __syncthreads();
#pragma unroll
    for (int kk = 0; kk < BK; kk += 32) {
      const int fr = lane & 15;
      const int q8 = (lane >> 4) * 8;
      f16x8 aH[TM], aL[TM], bH[TN], bL[TN];
#pragma unroll
      for (int i = 0; i < TM; ++i) {
        int off = (wm * (BM / 2) + i * 16 + fr) * BKP + kk + q8;
        aH[i] = *(const f16x8*)&sAh[off];
        aL[i] = *(const f16x8*)&sAl[off];
      }
#pragma unroll
      for (int j = 0; j < TN; ++j) {
        int off = (wn * (BN / 2) + j * 16 + fr) * BKP + kk + q8;
        bH[j] = *(const f16x8*)&sBh[off];
        bL[j] = *(const f16x8*)&sBl[off];
      }
#pragma unroll
      for (int i = 0; i < TM; ++i)
#pragma unroll
        for (int j = 0; j < TN; ++j) {
          acc[i][j] = __builtin_amdgcn_mfma_f32_16x16x32_f16(aH[i], bH[j], acc[i][j], 0, 0, 0);
          acc[i][j] = __builtin_amdgcn_mfma_f32_16x16x32_f16(aH[i], bL[j], acc[i][j], 0, 0, 0);
          acc[i][j] = __builtin_amdgcn_mfma_f32_16x16x32_f16(aL[i], bH[j], acc[i][j], 0, 0, 0);
        }
    }
  }
  const int rq = lane >> 4, cl = lane & 15;
#pragma unroll
  for (int i = 0; i < TM; ++i)
#pragma unroll
    for (int j = 0; j < TN; ++j)
#pragma unroll
      for (int r = 0; r < 4; ++r) {
        int row = m0 + wm * (BM / 2) + i * 16 + rq * 4 + r;
        int col = n0 + wn * (BN / 2) + j * 16 + cl;
        float v = acc[i][j][r];
        if (col < nReal) {
          if (bias1) v += bias1[col];
          if (bias2) v += bias2[col];
          if (relu) v = fmaxf(v, 0.f);
        } else {
          v = 0.f;
        }
        size_t o = (size_t)row * ldo + col;
        if (writeF32) {
          outF[o] = v;
        } else {
          f16 h = (f16)v;
          outH[o] = h;
          outL[o] = (f16)(v - (float)h);
        }
      }
}

// ---------------- conversion kernels ----------------
__global__ void conv_feats(const float* __restrict__ A, const float* __restrict__ O,
                           const float* __restrict__ LA, const int* __restrict__ EP,
                           f16* __restrict__ H, f16* __restrict__ L) {
  uint32_t idx = blockIdx.x * 256u + threadIdx.x;
  const uint32_t total = 4096u * 9280u;
  if (idx >= total) return;
  uint32_t b = idx / 9280u, c = idx - b * 9280u;
  float v;
  if (c < 4608u) v = A[(size_t)b * 4608 + c];
  else if (c < 9216u) v = O[(size_t)b * 4608 + (c - 4608u)];
  else if (c < 9224u) v = LA[(size_t)b * 8 + (c - 9216u)];
  else if (c == 9224u) v = (float)EP[0];
  else v = 0.f;
  f16 h = (f16)v;
  H[idx] = h;
  L[idx] = (f16)(v - (float)h);
}

// W [Kreal][Nreal] -> Bt hi/lo [Npad][Kpad], Bt[n][k]=W[k][n]
__global__ void convT_kernel(const float* __restrict__ W, int Kreal, int Nreal,
                             f16* __restrict__ BtH, f16* __restrict__ BtL, int Kpad) {
  __shared__ float tile[32][33];
  int k0 = blockIdx.x * 32, n0 = blockIdx.y * 32;
  int tx = threadIdx.x, ty = threadIdx.y;  // 32 x 8
  for (int r = 0; r < 32; r += 8) {
    int k = k0 + ty + r, n = n0 + tx;
    float v = (k < Kreal && n < Nreal) ? W[(size_t)k * Nreal + n] : 0.f;
    tile[ty + r][tx] = v;
  }
  __syncthreads();
  for (int r = 0; r < 32; r += 8) {
    int n = n0 + ty + r, k = k0 + tx;
    float v = tile[tx][ty + r];
    size_t o = (size_t)n * Kpad + k;
    f16 h = (f16)v;
    BtH[o] = h;
    BtL[o] = (f16)(v - (float)h);
  }
}

// all 8 head weights in one launch: W[h] [256][64] -> Bt [64][256] at offset h*64*256
__global__ void convT_heads(Ptr8 ws, f16* __restrict__ BtH, f16* __restrict__ BtL) {
  __shared__ float tile[32][33];
  int h = blockIdx.z;
  const float* W = ws.p[h];
  int k0 = blockIdx.x * 32, n0 = blockIdx.y * 32;
  int tx = threadIdx.x, ty = threadIdx.y;
  for (int r = 0; r < 32; r += 8) {
    int k = k0 + ty + r, n = n0 + tx;
    float v = (k < 256 && n < 64) ? W[(size_t)k * 64 + n] : 0.f;
    tile[ty + r][tx] = v;
  }
  __syncthreads();
  size_t base = (size_t)h * 64 * 256;
  for (int r = 0; r < 32; r += 8) {
    int n = n0 + ty + r, k = k0 + tx;
    float v = tile[tx][ty + r];
    size_t o = base + (size_t)n * 256 + k;
    f16 hh = (f16)v;
    BtH[o] = hh;
    BtL[o] = (f16)(v - (float)hh);
  }
}

// Bt_lstm [2048][1024]: cols 0-511 = Wih row n, cols 512-1023 = Whh row n
__global__ void conv_lstmB(const float* __restrict__ Wih, const float* __restrict__ Whh,
                           f16* __restrict__ H, f16* __restrict__ L) {
  uint32_t idx = blockIdx.x * 256u + threadIdx.x;
  uint32_t n = idx >> 10, k = idx & 1023u;
  float v = (k < 512u) ? Wih[(size_t)n * 512 + k] : Whh[(size_t)n * 512 + (k - 512u)];
  f16 h = (f16)v;
  H[idx] = h;
  L[idx] = (f16)(v - (float)h);
}

// h0 -> A_lstm cols 512..1023
__global__ void conv_h0(const float* __restrict__ h0, f16* __restrict__ H, f16* __restrict__ L) {
  uint32_t idx = blockIdx.x * 256u + threadIdx.x;
  uint32_t b = idx >> 9, j = idx & 511u;
  float v = h0[idx];
  size_t o = (size_t)b * 1024 + 512 + j;
  f16 h = (f16)v;
  H[o] = h;
  L[o] = (f16)(v - (float)h);
}

// LSTM pointwise: gates [4096][2048] (i,f,g,o) -> z hi/lo compact [4096][512]
__global__ void lstm_pointwise(const float* __restrict__ gates, const float* __restrict__ c0,
                               f16* __restrict__ zH, f16* __restrict__ zL) {
  uint32_t idx = blockIdx.x * 256u + threadIdx.x;
  uint32_t b = idx >> 9, n = idx & 511u;
  const float* g = gates + (size_t)b * 2048;
  float gi = g[n], gf = g[512 + n], gg = g[1024 + n], go = g[1536 + n];
  float si = 1.f / (1.f + expf(-gi));
  float sf = 1.f / (1.f + expf(-gf));
  float so = 1.f / (1.f + expf(-go));
  float c = sf * c0[idx] + si * tanhf(gg);
  float z = so * tanhf(c);
  f16 h = (f16)z;
  zH[idx] = h;
  zL[idx] = (f16)(z - (float)h);
}

__global__ void init_ent(float* __restrict__ out) {
  if (threadIdx.x == 0 && blockIdx.x == 0) out[32768] = 0.f;
}

__device__ inline double shfl_xor_dbl(double v, int m) {
  union { double d; int i[2]; } u;
  u.d = v;
  u.i[0] = __shfl_xor(u.i[0], m);
  u.i[1] = __shfl_xor(u.i[1], m);
  return u.d;
}

// ---------------- fused autoregressive decoder ----------------
// 256 blocks x 16 rows; per head: z1=relu(z@dW1+db1) -> logits=z1@Wk+bk ->
// sample (exact JAX threefry/gumbel) -> z=relu([z|act]@dWo+dbo).
// z/z1 in LDS hi/lo planes (stride padded for 2-way bank aliasing);
// weights read from global (L2-resident). K-order and MFMA triple order
// identical to the round-2 per-GEMM path -> bit-identical logits.
__global__ __launch_bounds__(256, 2) void decoder_fused(
    const f16* __restrict__ zH0, const f16* __restrict__ zL0,     // [4096][512]
    const f16* __restrict__ Bd1H, const f16* __restrict__ Bd1L,   // [256][512]
    const float* __restrict__ db1,
    const f16* __restrict__ BhH, const f16* __restrict__ BhL,     // [8][64][256]
    Ptr8 hb,
    const f16* __restrict__ BdoH, const f16* __restrict__ BdoL,   // [512][576]
    const float* __restrict__ dbo,
    Keys8 sk, int partitionable,
    float* __restrict__ out) {
  constexpr int ZS = 584;   // z plane stride (f16): 292 dw -> 4-bank row offset
  constexpr int Z1S = 264;  // z1 plane stride
  __shared__ f16 zbH[16 * ZS], zbL[16 * ZS];
  __shared__ f16 z1H[16 * Z1S], z1L[16 * Z1S];
  __shared__ float lgt[16 * 64];
  __shared__ float entSh[4];

  const int tid = threadIdx.x;
  const int wave = tid >> 6, lane = tid & 63;
  const int fr = lane & 15, rq = lane >> 4;
  const int q8 = rq * 8;
  const int rowG0 = blockIdx.x * 16;
  const f32x4 zero = {0.f, 0.f, 0.f, 0.f};

  // load initial z (cols 0..511) and zero pad cols 512..575
#pragma unroll
  for (int t = 0; t < 4; ++t) {
    int ch = t * 256 + tid;
    int r = ch >> 6, c8 = (ch & 63) * 8;
    *(f16x8*)&zbH[r * ZS + c8] = *(const f16x8*)&zH0[(size_t)(rowG0 + r) * 512 + c8];
    *(f16x8*)&zbL[r * ZS + c8] = *(const f16x8*)&zL0[(size_t)(rowG0 + r) * 512 + c8];
  }
  if (tid < 128) {
    int r = tid >> 3, c8 = 512 + (tid & 7) * 8;
    f16x8 zz = {0, 0, 0, 0, 0, 0, 0, 0};
    *(f16x8*)&zbH[r * ZS + c8] = zz;
    *(f16x8*)&zbL[r * ZS + c8] = zz;
  }

  float entAcc = 0.f;
  float logpAcc[4] = {0.f, 0.f, 0.f, 0.f};

  for (int h = 0; h < 8; ++h) {
    __syncthreads();  // zbuf ready (init load or prev stepD write)
    // ---- stepA: z1 = relu(z @ dW1 + db1); wave covers n in [wave*64, +64)
    {
      f32x4 acc[4];
#pragma unroll
      for (int j = 0; j < 4; ++j) acc[j] = zero;
      for (int k0 = 0; k0 < 512; k0 += 32) {
        f16x8 aH = *(const f16x8*)&zbH[fr * ZS + k0 + q8];
        f16x8 aL = *(const f16x8*)&zbL[fr * ZS + k0 + q8];
#pragma unroll
        for (int j = 0; j < 4; ++j) {
          int n = wave * 64 + j * 16 + fr;
          f16x8 bH = *(const f16x8*)&Bd1H[n * 512 + k0 + q8];
          f16x8 bL = *(const f16x8*)&Bd1L[n * 512 + k0 + q8];
          acc[j] = __builtin_amdgcn_mfma_f32_16x16x32_f16(aH, bH, acc[j], 0, 0, 0);
          acc[j] = __builtin_amdgcn_mfma_f32_16x16x32_f16(aH, bL, acc[j], 0, 0, 0);
          acc[j] = __builtin_amdgcn_mfma_f32_16x16x32_f16(aL, bH, acc[j], 0, 0, 0);
        }
      }
#pragma unroll
      for (int j = 0; j < 4; ++j) {
        int col = wave * 64 + j * 16 + fr;
        float bb = db1[col];
#pragma unroll
        for (int r = 0; r < 4; ++r) {
          float v = fmaxf(acc[j][r] + bb, 0.f);
          int row = rq * 4 + r;
          f16 hv = (f16)v;
          z1H[row * Z1S + col] = hv;
          z1L[row * Z1S + col] = (f16)(v - (float)hv);
        }
      }
    }
    __syncthreads();
    // ---- stepB: logits = z1 @ Wk + bk; wave covers n in [wave*16, +16)
    {
      f32x4 acc = zero;
      const f16* BH = BhH + (size_t)h * 64 * 256;
      const f16* BL = BhL + (size_t)h * 64 * 256;
      int n = wave * 16 + fr;
      for (int k0 = 0; k0 < 256; k0 += 32) {
        f16x8 aH = *(const f16x8*)&z1H[fr * Z1S + k0 + q8];
        f16x8 aL = *(const f16x8*)&z1L[fr * Z1S + k0 + q8];
        f16x8 bH = *(const f16x8*)&BH[n * 256 + k0 + q8];
        f16x8 bL = *(const f16x8*)&BL[n * 256 + k0 + q8];
        acc = __builtin_amdgcn_mfma_f32_16x16x32_f16(aH, bH, acc, 0, 0, 0);
        acc = __builtin_amdgcn_mfma_f32_16x16x32_f16(aH, bL, acc, 0, 0, 0);
        acc = __builtin_amdgcn_mfma_f32_16x16x32_f16(aL, bH, acc, 0, 0, 0);
      }
      float bb = hb.p[h][n];
#pragma unroll
      for (int r = 0; r < 4; ++r) lgt[(rq * 4 + r) * 64 + n] = acc[r] + bb;
    }
    __syncthreads();
    // ---- stepC: sample rows wave*4..wave*4+3 (lane = category)
    for (int rr = 0; rr < 4; ++rr) {
      int row = wave * 4 + rr;
      int b = rowG0 + row;
      float l = lgt[row * 64 + lane];
      uint32_t i = (uint32_t)b * 64u + (uint32_t)lane;
      uint32_t bits;
      if (partitionable) {
        uint32_t o0, o1;
        tf2x32(sk.k[h][0], sk.k[h][1], 0u, i, o0, o1);
        bits = o0 ^ o1;
      } else {
        const uint32_t Hh = 131072u;
        uint32_t c0, c1, o0, o1;
        int pick;
        if (i < Hh) { c0 = i; c1 = i + Hh; pick = 0; }
        else        { c0 = i - Hh; c1 = i; pick = 1; }
        tf2x32(sk.k[h][0], sk.k[h][1], c0, c1, o0, o1);
        bits = pick ? o1 : o0;
      }
      uint32_t ub = (bits >> 9) | 0x3f800000u;
      float u;
      __builtin_memcpy(&u, &ub, 4);
      u -= 1.0f;
      if (u == 0.0f) u = 1.17549435e-38f;
      double gum = -log(-log((double)u));
      double s = (double)l + gum;
      int bi = lane;
      double bv = s;
#pragma unroll
      for (int off = 1; off < 64; off <<= 1) {
        double ov = shfl_xor_dbl(bv, off);
        int oi = __shfl_xor(bi, off);
        if (ov > bv || (ov == bv && oi < bi)) { bv = ov; bi = oi; }
      }
      int act = bi;
      float m = l;
#pragma unroll
      for (int off = 1; off < 64; off <<= 1) m = fmaxf(m, __shfl_xor(m, off));
      float e = expf(l - m);
      float S = e, D = e * l;
#pragma unroll
      for (int off = 1; off < 64; off <<= 1) {
        S += __shfl_xor(S, off);
        D += __shfl_xor(D, off);
      }
      float M = m + logf(S);
      entAcc += (M - D / S);
      float l_act = __shfl(l, act);
      logpAcc[rr] += (l_act - M);
      if (lane == 0) {
        out[(size_t)b * 8 + h] = (float)act;
        zbH[row * ZS + 512] = (f16)act;
        zbL[row * ZS + 512] = (f16)0.f;
      }
    }
    __syncthreads();
    // ---- stepD: z_new = relu([z|act] @ dWo + dbo); wave covers n in [wave*128, +128)
    {
      f32x4 accD[8];
#pragma unroll
      for (int j = 0; j < 8; ++j) accD[j] = zero;
      for (int k0 = 0; k0 < 576; k0 += 32) {
        f16x8 aH = *(const f16x8*)&zbH[fr * ZS + k0 + q8];
        f16x8 aL = *(const f16x8*)&zbL[fr * ZS + k0 + q8];
#pragma unroll
        for (int j = 0; j < 8; ++j) {
          int n = wave * 128 + j * 16 + fr;
          f16x8 bH = *(const f16x8*)&BdoH[n * 576 + k0 + q8];
          f16x8 bL = *(const f16x8*)&BdoL[n * 576 + k0 + q8];
          accD[j] = __builtin_amdgcn_mfma_f32_16x16x32_f16(aH, bH, accD[j], 0, 0, 0);
          accD[j] = __builtin_amdgcn_mfma_f32_16x16x32_f16(aH, bL, accD[j], 0, 0, 0);
          accD[j] = __builtin_amdgcn_mfma_f32_16x16x32_f16(aL, bH, accD[j], 0, 0, 0);
        }
      }
      __syncthreads();  // all waves done reading old zbuf
#pragma unroll
      for (int j = 0; j < 8; ++j) {
        int col = wave * 128 + j * 16 + fr;
        float bb = dbo[col];
#pragma unroll
        for (int r = 0; r < 4; ++r) {
          float v = fmaxf(accD[j][r] + bb, 0.f);
          int row = rq * 4 + r;
          f16 hv = (f16)v;
          zbH[row * ZS + col] = hv;
          zbL[row * ZS + col] = (f16)(v - (float)hv);
        }
      }
    }
  }
  // finalize: entropy (block atomic) + logp (direct)
  if (lane == 0) entSh[wave] = entAcc;
  __syncthreads();
  if (tid == 0) atomicAdd(&out[32768], entSh[0] + entSh[1] + entSh[2] + entSh[3]);
  if (lane == 0)
    for (int rr = 0; rr < 4; ++rr) out[32769 + rowG0 + wave * 4 + rr] = logpAcc[rr];
}

// ---------------- host ----------------
extern "C" void kernel_launch(void* const* d_in, const int* in_sizes, int n_in,
                              void* d_out, int out_size, void* d_ws, size_t ws_size,
                              hipStream_t stream) {
  (void)in_sizes; (void)out_size; (void)ws_size;
  const float* actual = (const float*)d_in[0];
  const float* object = (const float*)d_in[1];
  const float* lastA = (const float*)d_in[2];
  const int* ep = (const int*)d_in[3];
  const float* W1 = (const float*)d_in[4];
  const float* b1 = (const float*)d_in[5];
  const float* W2 = (const float*)d_in[6];
  const float* b2 = (const float*)d_in[7];
  const float* W3 = (const float*)d_in[8];
  const float* b3 = (const float*)d_in[9];
  const float* Wih = (const float*)d_in[10];
  const float* Whh = (const float*)d_in[11];
  const float* bih = (const float*)d_in[12];
  const float* bhh = (const float*)d_in[13];
  const float* h0 = (const float*)d_in[14];
  const float* c0 = (const float*)d_in[15];
  const float* dW1 = (const float*)d_in[16];
  const float* db1 = (const float*)d_in[17];
  const float* headW[8];
  const float* headb[8];
  const float *dWo, *dbo;
  if (n_in >= 36) {
    for (int h = 0; h < 8; ++h) headW[h] = (const float*)d_in[18 + h];
    for (int h = 0; h < 8; ++h) headb[h] = (const float*)d_in[26 + h];
    dWo = (const float*)d_in[34];
    dbo = (const float*)d_in[35];
  } else {
    const float* hw = (const float*)d_in[18];
    const float* hbp = (const float*)d_in[19];
    for (int h = 0; h < 8; ++h) { headW[h] = hw + (size_t)h * 256 * 64; headb[h] = hbp + (size_t)h * 64; }
    dWo = (const float*)d_in[20];
    dbo = (const float*)d_in[21];
  }

  constexpr int Bq = 4096;
  constexpr int K1 = 9280, N1 = 3584, N1r = 3518;
  constexpr int K2 = 3584, N2 = 1408, N2r = 1342;
  constexpr int K3 = 1408, N3 = 512;
  constexpr int KL = 1024, NL = 2048;
  constexpr int KD1 = 512, ND1 = 256;
  constexpr int KH = 256;
  constexpr int KDO = 576, NDO = 512;

  uint8_t* w = (uint8_t*)d_ws;
  size_t off = 0;
  auto alloc = [&](size_t bytes) -> void* {
    off = (off + 1023) & ~(size_t)1023;
    void* p = w + off;
    off += bytes;
    return p;
  };
  f16* A1h = (f16*)alloc((size_t)Bq * K1 * 2);
  f16* A1l = (f16*)alloc((size_t)Bq * K1 * 2);
  f16* Bt1h = (f16*)alloc((size_t)N1 * K1 * 2);
  f16* Bt1l = (f16*)alloc((size_t)N1 * K1 * 2);
  f16* x1h = (f16*)alloc((size_t)Bq * K2 * 2);
  f16* x1l = (f16*)alloc((size_t)Bq * K2 * 2);
  f16* Bt2h = (f16*)alloc((size_t)N2 * K2 * 2);
  f16* Bt2l = (f16*)alloc((size_t)N2 * K2 * 2);
  // pool aliases the A1 region (dead after GEMM1)
  size_t poff = 0;
  auto palloc = [&](size_t bytes) -> void* {
    poff = (poff + 1023) & ~(size_t)1023;
    void* p = w + poff;
    poff += bytes;
    return p;
  };
  f16* x2h = (f16*)palloc((size_t)Bq * K3 * 2);
  f16* x2l = (f16*)palloc((size_t)Bq * K3 * 2);
  f16* Bt3h = (f16*)palloc((size_t)N3 * K3 * 2);
  f16* Bt3l = (f16*)palloc((size_t)N3 * K3 * 2);
  f16* ALh = (f16*)palloc((size_t)Bq * KL * 2);
  f16* ALl = (f16*)palloc((size_t)Bq * KL * 2);
  f16* BLh = (f16*)palloc((size_t)NL * KL * 2);
  f16* BLl = (f16*)palloc((size_t)NL * KL * 2);
  float* gates = (float*)palloc((size_t)Bq * NL * 4);
  f16* zAH = (f16*)palloc((size_t)Bq * 512 * 2);
  f16* zAL = (f16*)palloc((size_t)Bq * 512 * 2);
  f16* Btd1h = (f16*)palloc((size_t)ND1 * KD1 * 2);
  f16* Btd1l = (f16*)palloc((size_t)ND1 * KD1 * 2);
  f16* Bthh = (f16*)palloc((size_t)8 * 64 * KH * 2);
  f16* Bthl = (f16*)palloc((size_t)8 * 64 * KH * 2);
  f16* Btdoh = (f16*)palloc((size_t)NDO * KDO * 2);
  f16* Btdol = (f16*)palloc((size_t)NDO * KDO * 2);

  // ---- subkeys (host, seed 42 only) ----
  uint32_t k0 = 0u, k1 = 42u;
  Keys8 sk;
  for (int h = 0; h < 8; ++h) {
    if (kPartitionable) {
      uint32_t a0, a1, b0v, b1v;
      tf2x32(k0, k1, 0u, 0u, a0, a1);
      tf2x32(k0, k1, 0u, 1u, b0v, b1v);
      sk.k[h][0] = b0v; sk.k[h][1] = b1v;
      k0 = a0; k1 = a1;
    } else {
      uint32_t a0, a1, b0v, b1v;
      tf2x32(k0, k1, 0u, 2u, a0, a1);
      tf2x32(k0, k1, 1u, 3u, b0v, b1v);
      sk.k[h][0] = a1; sk.k[h][1] = b1v;
      k0 = a0; k1 = b0v;
    }
  }
  Ptr8 hws, hbs;
  for (int h = 0; h < 8; ++h) { hws.p[h] = headW[h]; hbs.p[h] = headb[h]; }

  dim3 blk(256);
  dim3 tblk(32, 8);

  conv_feats<<<(4096u * 9280u + 255) / 256, blk, 0, stream>>>(actual, object, lastA, ep, A1h, A1l);
  convT_kernel<<<dim3(K1 / 32, N1 / 32), tblk, 0, stream>>>(W1, 9225, 3518, Bt1h, Bt1l, K1);
  convT_kernel<<<dim3(K2 / 32, N2 / 32), tblk, 0, stream>>>(W2, 3518, 1342, Bt2h, Bt2l, K2);

  gemm_split<128, 128><<<dim3(Bq / 128, N1 / 128), blk, 0, stream>>>(
      A1h, A1l, K1, Bt1h, Bt1l, K1, K1, b1, nullptr, N1r, 1, 0, nullptr, x1h, x1l, K2);

  // pool conversions (A1 dead now)
  convT_kernel<<<dim3(K3 / 32, N3 / 32), tblk, 0, stream>>>(W3, 1342, 512, Bt3h, Bt3l, K3);
  conv_lstmB<<<(2048u * 1024u) / 256, blk, 0, stream>>>(Wih, Whh, BLh, BLl);
  conv_h0<<<(4096u * 512u) / 256, blk, 0, stream>>>(h0, ALh, ALl);
  convT_kernel<<<dim3(KD1 / 32, ND1 / 32), tblk, 0, stream>>>(dW1, 512, 256, Btd1h, Btd1l, KD1);
  convT_kernel<<<dim3(KDO / 32, NDO / 32), tblk, 0, stream>>>(dWo, 513, 512, Btdoh, Btdol, KDO);
  convT_heads<<<dim3(KH / 32, 2, 8), tblk, 0, stream>>>(hws, Bthh, Bthl);
  init_ent<<<1, 64, 0, stream>>>((float*)d_out);

  gemm_split<128, 128><<<dim3(Bq / 128, N2 / 128), blk, 0, stream>>>(
      x1h, x1l, K2, Bt2h, Bt2l, K2, K2, b2, nullptr, N2r, 1, 0, nullptr, x2h, x2l, K3);
  gemm_split<128, 128><<<dim3(Bq / 128, N3 / 128), blk, 0, stream>>>(
      x2h, x2l, K3, Bt3h, Bt3l, K3, K3, b3, nullptr, N3, 1, 0, nullptr, ALh, ALl, KL);
  gemm_split<128, 128><<<dim3(Bq / 128, NL / 128), blk, 0, stream>>>(
      ALh, ALl, KL, BLh, BLl, KL, KL, bih, bhh, NL, 0, 1, gates, nullptr, nullptr, NL);
  lstm_pointwise<<<(4096u * 512u) / 256, blk, 0, stream>>>(gates, c0, zAH, zAL);

  decoder_fused<<<256, blk, 0, stream>>>(
      zAH, zAL, Btd1h, Btd1l, db1, Bthh, Bthl, hbs, Btdoh, Btdol, dbo,
      sk, kPartitionable, (float*)d_out);
}

// Round 4
// 1873.503 us; speedup vs baseline: 1.1842x; 1.1842x over previous
//
#include <hip/hip_runtime.h>
#include <cstdint>
#include <cstring>

typedef _Float16 f16;
typedef _Float16 f16x8 __attribute__((ext_vector_type(8)));
typedef float f32x4 __attribute__((ext_vector_type(4)));

// ---- JAX threefry scheme: 1 = partitionable (jax >= 0.4.36 default), 0 = original
static constexpr int kPartitionable = 1;

struct Ptr8 { const float* p[8]; };

// Swizzled storage for all f16 hi/lo GEMM operands:
//   element (row r, col k) lives at physical k ^ ((r&7)<<3)
// (16B-chunk permutation within each aligned 128B group). This makes a wave's
// 8-row x 64-col staging block exactly lane-ordered for global_load_lds
// (dest = LDS base + lane*16) and gives conflict-uniform LDS fragment reads.
__device__ __host__ __forceinline__ int swz(int r, int k) {
  return k ^ ((r & 7) << 3);
}

// async 16B global -> LDS (no VGPR roundtrip); dest = ldsbase + lane*16
__device__ __forceinline__ void gload16(const void* g, void* l) {
  __builtin_amdgcn_global_load_lds(
      (const __attribute__((address_space(1))) unsigned int*)g,
      (__attribute__((address_space(3))) unsigned int*)l, 16, 0, 0);
}

// ---------------- Threefry-2x32 (host + device) ----------------
__host__ __device__ inline void tf2x32(uint32_t k0, uint32_t k1,
                                       uint32_t x0, uint32_t x1,
                                       uint32_t& o0, uint32_t& o1) {
  uint32_t ks[3] = {k0, k1, k0 ^ k1 ^ 0x1BD11BDAu};
  uint32_t v0 = x0 + ks[0], v1 = x1 + ks[1];
  const int r0[4] = {13, 15, 26, 6};
  const int r1[4] = {17, 29, 16, 24};
  for (int g = 0; g < 5; ++g) {
    const int* rr = (g & 1) ? r1 : r0;
    for (int j = 0; j < 4; ++j) {
      v0 += v1;
      v1 = (v1 << rr[j]) | (v1 >> (32 - rr[j]));
      v1 ^= v0;
    }
    v0 += ks[(g + 1) % 3];
    v1 += ks[(g + 2) % 3] + (uint32_t)(g + 1);
  }
  o0 = v0; o1 = v1;
}

// ---------------- split-fp16 MFMA GEMM ----------------
// C[m][n] = sum_k A[m][k]*Bt[n][k]; A/Bt are (hi,lo) fp16 pairs in swizzled
// layout. 3 MFMAs per fragment pair: hi*hi + hi*lo + lo*hi (fp32 accumulate).
// Staging: global_load_lds dwordx4, one 1KB wave-load per 8 rows.
template <int BM, int BN>
__global__ __launch_bounds__(256, 2) void gemm_split(
    const f16* __restrict__ Ah, const f16* __restrict__ Al, int lda,
    const f16* __restrict__ Bh, const f16* __restrict__ Bl, int ldb,
    int K,
    const float* __restrict__ bias1, const float* __restrict__ bias2,
    int nReal, int relu, int writeF32,
    float* __restrict__ outF, f16* __restrict__ outH, f16* __restrict__ outL,
    int ldo) {
  constexpr int BK = 64;
  constexpr int TM = BM / 32;
  constexpr int TN = BN / 32;
  static_assert(BM == BN, "square tiles only");
  __shared__ f16 sAh[BM * BK];
  __shared__ f16 sAl[BM * BK];
  __shared__ f16 sBh[BN * BK];
  __shared__ f16 sBl[BN * BK];

  const int tid = threadIdx.x;
  const int wave = tid >> 6;
  const int lane = tid & 63;
  const int wm = wave & 1, wn = wave >> 1;
  const int m0 = blockIdx.x * BM;
  const int n0 = blockIdx.y * BN;

  f32x4 acc[TM][TN];
  const f32x4 zero = {0.f, 0.f, 0.f, 0.f};
#pragma unroll
  for (int i = 0; i < TM; ++i)
#pragma unroll
    for (int j = 0; j < TN; ++j) acc[i][j] = zero;

  // staging: wave 0->sAh, 1->sAl, 2->sBh, 3->sBl   (BM==BN so same shape)
  const f16* src;
  f16* dst;
  int ld, base;
  if (wave == 0)      { src = Ah; dst = sAh; ld = lda; base = m0; }
  else if (wave == 1) { src = Al; dst = sAl; ld = lda; base = m0; }
  else if (wave == 2) { src = Bh; dst = sBh; ld = ldb; base = n0; }
  else                { src = Bl; dst = sBl; ld = ldb; base = n0; }
  constexpr int NITER = BM / 8;  // 1KB wave-loads per tile (8 rows each)
  const f16* gbase = src + (size_t)(base + (lane >> 3)) * ld + (lane & 7) * 8;

  const int fr = lane & 15;
  const int q8 = (lane >> 4) * 8;
  const int sw = (fr & 7) << 3;

  for (int k0 = 0; k0 < K; k0 += BK) {
    __syncthreads();  // all waves done reading LDS from prev iter
#pragma unroll
    for (int j = 0; j < NITER; ++j)
      gload16(gbase + (size_t)(j * 8) * ld + k0, dst + j * 512);
    __syncthreads();  // drains vmcnt: staged data visible
#pragma unroll
    for (int kk = 0; kk < BK; kk += 32) {
      const int kf = (kk + q8) ^ sw;  // un-swizzle fragment chunk
      f16x8 aH[TM], aL[TM], bH[TN], bL[TN];
#pragma unroll
      for (int i = 0; i < TM; ++i) {
        int off = (wm * (BM / 2) + i * 16 + fr) * BK + kf;
        aH[i] = *(const f16x8*)&sAh[off];
        aL[i] = *(const f16x8*)&sAl[off];
      }
#pragma unroll
      for (int j = 0; j < TN; ++j) {
        int off = (wn * (BN / 2) + j * 16 + fr) * BK + kf;
        bH[j] = *(const f16x8*)&sBh[off];
        bL[j] = *(const f16x8*)&sBl[off];
      }
#pragma unroll
      for (int i = 0; i < TM; ++i)
#pragma unroll
        for (int j = 0; j < TN; ++j) {
          acc[i][j] = __builtin_amdgcn_mfma_f32_16x16x32_f16(aH[i], bH[j], acc[i][j], 0, 0, 0);
          acc[i][j] = __builtin_amdgcn_mfma_f32_16x16x32_f16(aH[i], bL[j], acc[i][j], 0, 0, 0);
          acc[i][j] = __builtin_amdgcn_mfma_f32_16x16x32_f16(aL[i], bH[j], acc[i][j], 0, 0, 0);
        }
    }
  }
  // epilogue: C/D layout col=lane&15, row=(lane>>4)*4+reg (m89/m91 verified)
  const int rq = lane >> 4, cl = lane & 15;
#pragma unroll
  for (int i = 0; i < TM; ++i)
#pragma unroll
    for (int j = 0; j < TN; ++j)
#pragma unroll
      for (int r = 0; r < 4; ++r) {
        int row = m0 + wm * (BM / 2) + i * 16 + rq * 4 + r;
        int col = n0 + wn * (BN / 2) + j * 16 + cl;
        float v = acc[i][j][r];
        if (col < nReal) {
          if (bias1) v += bias1[col];
          if (bias2) v += bias2[col];
          if (relu) v = fmaxf(v, 0.f);
        } else {
          v = 0.f;
        }
        if (writeF32) {
          outF[(size_t)row * ldo + col] = v;
        } else {
          size_t o = (size_t)row * ldo + swz(row, col);
          f16 h = (f16)v;
          outH[o] = h;
          outL[o] = (f16)(v - (float)h);
        }
      }
}

// ---------------- conversion kernels (all write swizzled layout) ----------------
// feats = [actual | objective | last_action | ep | zeros] -> hi/lo fp16 [4096][9280]
__global__ void conv_feats(const float* __restrict__ A, const float* __restrict__ O,
                           const float* __restrict__ LA, const int* __restrict__ EP,
                           f16* __restrict__ H, f16* __restrict__ L) {
  uint32_t idx = blockIdx.x * 256u + threadIdx.x;
  const uint32_t total = 4096u * 9280u;
  if (idx >= total) return;
  uint32_t b = idx / 9280u, c = idx - b * 9280u;
  float v;
  if (c < 4608u) v = A[(size_t)b * 4608 + c];
  else if (c < 9216u) v = O[(size_t)b * 4608 + (c - 4608u)];
  else if (c < 9224u) v = LA[(size_t)b * 8 + (c - 9216u)];
  else if (c == 9224u) v = (float)EP[0];
  else v = 0.f;
  size_t o = (size_t)b * 9280 + swz((int)b, (int)c);
  f16 h = (f16)v;
  H[o] = h;
  L[o] = (f16)(v - (float)h);
}

// W [Kreal][Nreal] -> Bt hi/lo [Npad][Kpad], Bt[n][k]=W[k][n]
__global__ void convT_kernel(const float* __restrict__ W, int Kreal, int Nreal,
                             f16* __restrict__ BtH, f16* __restrict__ BtL, int Kpad) {
  __shared__ float tile[32][33];
  int k0 = blockIdx.x * 32, n0 = blockIdx.y * 32;
  int tx = threadIdx.x, ty = threadIdx.y;  // 32 x 8
  for (int r = 0; r < 32; r += 8) {
    int k = k0 + ty + r, n = n0 + tx;
    float v = (k < Kreal && n < Nreal) ? W[(size_t)k * Nreal + n] : 0.f;
    tile[ty + r][tx] = v;
  }
  __syncthreads();
  for (int r = 0; r < 32; r += 8) {
    int n = n0 + ty + r, k = k0 + tx;
    float v = tile[tx][ty + r];
    size_t o = (size_t)n * Kpad + swz(n, k);
    f16 h = (f16)v;
    BtH[o] = h;
    BtL[o] = (f16)(v - (float)h);
  }
}

// all 8 head weights in one launch: W[h] [256][64] -> Bt [64][256] at offset h*64*256
__global__ void convT_heads(Ptr8 ws, f16* __restrict__ BtH, f16* __restrict__ BtL) {
  __shared__ float tile[32][33];
  int h = blockIdx.z;
  const float* W = ws.p[h];
  int k0 = blockIdx.x * 32, n0 = blockIdx.y * 32;
  int tx = threadIdx.x, ty = threadIdx.y;
  for (int r = 0; r < 32; r += 8) {
    int k = k0 + ty + r, n = n0 + tx;
    float v = (k < 256 && n < 64) ? W[(size_t)k * 64 + n] : 0.f;
    tile[ty + r][tx] = v;
  }
  __syncthreads();
  size_t base = (size_t)h * 64 * 256;
  for (int r = 0; r < 32; r += 8) {
    int n = n0 + ty + r, k = k0 + tx;
    float v = tile[tx][ty + r];
    size_t o = base + (size_t)n * 256 + swz(n, k);
    f16 hh = (f16)v;
    BtH[o] = hh;
    BtL[o] = (f16)(v - (float)hh);
  }
}

// Bt_lstm [2048][1024]: cols 0-511 = Wih row n, cols 512-1023 = Whh row n
__global__ void conv_lstmB(const float* __restrict__ Wih, const float* __restrict__ Whh,
                           f16* __restrict__ H, f16* __restrict__ L) {
  uint32_t idx = blockIdx.x * 256u + threadIdx.x;
  uint32_t n = idx >> 10, k = idx & 1023u;
  float v = (k < 512u) ? Wih[(size_t)n * 512 + k] : Whh[(size_t)n * 512 + (k - 512u)];
  size_t o = (size_t)n * 1024 + swz((int)n, (int)k);
  f16 h = (f16)v;
  H[o] = h;
  L[o] = (f16)(v - (float)h);
}

// h0 -> A_lstm cols 512..1023
__global__ void conv_h0(const float* __restrict__ h0, f16* __restrict__ H, f16* __restrict__ L) {
  uint32_t idx = blockIdx.x * 256u + threadIdx.x;
  uint32_t b = idx >> 9, j = idx & 511u;
  float v = h0[idx];
  size_t o = (size_t)b * 1024 + swz((int)b, (int)(512 + j));
  f16 h = (f16)v;
  H[o] = h;
  L[o] = (f16)(v - (float)h);
}

// LSTM pointwise: gates [4096][2048] (i,f,g,o) -> z hi/lo into zcat (ld 576)
__global__ void lstm_pointwise(const float* __restrict__ gates, const float* __restrict__ c0,
                               f16* __restrict__ zH, f16* __restrict__ zL) {
  uint32_t idx = blockIdx.x * 256u + threadIdx.x;
  uint32_t b = idx >> 9, n = idx & 511u;
  const float* g = gates + (size_t)b * 2048;
  float gi = g[n], gf = g[512 + n], gg = g[1024 + n], go = g[1536 + n];
  float si = 1.f / (1.f + expf(-gi));
  float sf = 1.f / (1.f + expf(-gf));
  float so = 1.f / (1.f + expf(-go));
  float c = sf * c0[idx] + si * tanhf(gg);
  float z = so * tanhf(c);
  size_t o = (size_t)b * 576 + swz((int)b, (int)n);
  f16 h = (f16)z;
  zH[o] = h;
  zL[o] = (f16)(z - (float)h);
}

// init: zero zcat pad cols 513..575 (both buffers), ws_logp, ws_entropy
__global__ void init_ws(f16* zAH, f16* zAL, f16* zBH, f16* zBL,
                        float* wsLogp, float* wsEnt) {
  uint32_t idx = blockIdx.x * 256u + threadIdx.x;
  if (idx < 4096u * 63u) {
    uint32_t b = idx / 63u, c = 513u + idx - b * 63u;
    size_t o = (size_t)b * 576 + swz((int)b, (int)c);
    zAH[o] = (f16)0.f; zAL[o] = (f16)0.f; zBH[o] = (f16)0.f; zBL[o] = (f16)0.f;
  }
  if (idx < 4096u) wsLogp[idx] = 0.f;
  if (idx == 0) *wsEnt = 0.f;
}

__device__ inline double shfl_xor_dbl(double v, int m) {
  union { double d; int i[2]; } u;
  u.d = v;
  u.i[0] = __shfl_xor(u.i[0], m);
  u.i[1] = __shfl_xor(u.i[1], m);
  return u.d;
}

// one wave per batch row; 64 lanes <-> 64 categories
__global__ void sample_head(const float* __restrict__ logits,  // ld 64, linear f32
                            uint32_t sk0, uint32_t sk1, int head, int partitionable,
                            float* __restrict__ outAct,
                            f16* __restrict__ zH, f16* __restrict__ zL,  // current zcat
                            float* __restrict__ wsLogp, float* __restrict__ wsEnt) {
  int wave = threadIdx.x >> 6, lane = threadIdx.x & 63;
  int b = blockIdx.x * 4 + wave;
  float l = logits[(size_t)b * 64 + lane];

  // ---- gumbel bits per (b,lane) ----
  uint32_t i = (uint32_t)b * 64u + (uint32_t)lane;
  uint32_t bits;
  if (partitionable) {
    uint32_t o0, o1;
    tf2x32(sk0, sk1, 0u, i, o0, o1);
    bits = o0 ^ o1;
  } else {
    const uint32_t H = 131072u;  // (4096*64)/2
    uint32_t c0, c1, o0, o1;
    int pick;
    if (i < H) { c0 = i; c1 = i + H; pick = 0; }
    else       { c0 = i - H; c1 = i; pick = 1; }
    tf2x32(sk0, sk1, c0, c1, o0, o1);
    bits = pick ? o1 : o0;
  }
  uint32_t ub = (bits >> 9) | 0x3f800000u;
  float u;
  __builtin_memcpy(&u, &ub, 4);
  u -= 1.0f;
  if (u == 0.0f) u = 1.17549435e-38f;
  double gum = -log(-log((double)u));
  double s = (double)l + gum;

  // ---- argmax (first index wins on ties) ----
  int bi = lane;
  double bv = s;
#pragma unroll
  for (int off = 1; off < 64; off <<= 1) {
    double ov = shfl_xor_dbl(bv, off);
    int oi = __shfl_xor(bi, off);
    if (ov > bv || (ov == bv && oi < bi)) { bv = ov; bi = oi; }
  }
  int act = bi;

  // ---- softmax stats ----
  float m = l;
#pragma unroll
  for (int off = 1; off < 64; off <<= 1) m = fmaxf(m, __shfl_xor(m, off));
  float e = expf(l - m);
  float S = e, D = e * l;
#pragma unroll
  for (int off = 1; off < 64; off <<= 1) {
    S += __shfl_xor(S, off);
    D += __shfl_xor(D, off);
  }
  float M = m + logf(S);
  float Hrow = M - D / S;
  float l_act = __shfl(l, act);

  if (lane == 0) {
    outAct[(size_t)b * 8 + head] = (float)act;
    wsLogp[b] += (l_act - M);
    size_t zo = (size_t)b * 576 + swz(b, 512);
    zH[zo] = (f16)act;  // act <= 63, exact in fp16
    zL[zo] = (f16)0.f;
  }
  __shared__ float hs[4];
  if (lane == 0) hs[wave] = Hrow;
  __syncthreads();
  if (threadIdx.x == 0) atomicAdd(wsEnt, hs[0] + hs[1] + hs[2] + hs[3]);
}

__global__ void finalize_out(const float* __restrict__ wsEnt, const float* __restrict__ wsLogp,
                             float* __restrict__ out) {
  uint32_t idx = blockIdx.x * 256u + threadIdx.x;
  if (idx == 0) out[32768] = *wsEnt;
  if (idx < 4096u) out[32769 + idx] = wsLogp[idx];
}

// ---------------- host ----------------
extern "C" void kernel_launch(void* const* d_in, const int* in_sizes, int n_in,
                              void* d_out, int out_size, void* d_ws, size_t ws_size,
                              hipStream_t stream) {
  (void)in_sizes; (void)out_size; (void)ws_size;
  const float* actual = (const float*)d_in[0];
  const float* object = (const float*)d_in[1];
  const float* lastA = (const float*)d_in[2];
  const int* ep = (const int*)d_in[3];
  const float* W1 = (const float*)d_in[4];
  const float* b1 = (const float*)d_in[5];
  const float* W2 = (const float*)d_in[6];
  const float* b2 = (const float*)d_in[7];
  const float* W3 = (const float*)d_in[8];
  const float* b3 = (const float*)d_in[9];
  const float* Wih = (const float*)d_in[10];
  const float* Whh = (const float*)d_in[11];
  const float* bih = (const float*)d_in[12];
  const float* bhh = (const float*)d_in[13];
  const float* h0 = (const float*)d_in[14];
  const float* c0 = (const float*)d_in[15];
  const float* dW1 = (const float*)d_in[16];
  const float* db1 = (const float*)d_in[17];
  const float* headW[8];
  const float* headb[8];
  const float *dWo, *dbo;
  if (n_in >= 36) {
    for (int h = 0; h < 8; ++h) headW[h] = (const float*)d_in[18 + h];
    for (int h = 0; h < 8; ++h) headb[h] = (const float*)d_in[26 + h];
    dWo = (const float*)d_in[34];
    dbo = (const float*)d_in[35];
  } else {
    const float* hw = (const float*)d_in[18];
    const float* hbp = (const float*)d_in[19];
    for (int h = 0; h < 8; ++h) { headW[h] = hw + (size_t)h * 256 * 64; headb[h] = hbp + (size_t)h * 64; }
    dWo = (const float*)d_in[20];
    dbo = (const float*)d_in[21];
  }

  constexpr int Bq = 4096;
  constexpr int K1 = 9280, N1 = 3584, N1r = 3518;
  constexpr int K2 = 3584, N2 = 1408, N2r = 1342;
  constexpr int K3 = 1408, N3 = 512;
  constexpr int KL = 1024, NL = 2048;
  constexpr int KD1 = 512, ND1 = 256;
  constexpr int KH = 256;
  constexpr int KDO = 576, NDO = 512;

  uint8_t* w = (uint8_t*)d_ws;
  size_t off = 0;
  auto alloc = [&](size_t bytes) -> void* {
    off = (off + 1023) & ~(size_t)1023;
    void* p = w + off;
    off += bytes;
    return p;
  };
  f16* A1h = (f16*)alloc((size_t)Bq * K1 * 2);
  f16* A1l = (f16*)alloc((size_t)Bq * K1 * 2);
  f16* Bt1h = (f16*)alloc((size_t)N1 * K1 * 2);
  f16* Bt1l = (f16*)alloc((size_t)N1 * K1 * 2);
  f16* x1h = (f16*)alloc((size_t)Bq * K2 * 2);
  f16* x1l = (f16*)alloc((size_t)Bq * K2 * 2);
  f16* Bt2h = (f16*)alloc((size_t)N2 * K2 * 2);
  f16* Bt2l = (f16*)alloc((size_t)N2 * K2 * 2);
  // pool aliases the A1 region (dead after GEMM1)
  size_t poff = 0;
  auto palloc = [&](size_t bytes) -> void* {
    poff = (poff + 1023) & ~(size_t)1023;
    void* p = w + poff;
    poff += bytes;
    return p;
  };
  f16* x2h = (f16*)palloc((size_t)Bq * K3 * 2);
  f16* x2l = (f16*)palloc((size_t)Bq * K3 * 2);
  f16* Bt3h = (f16*)palloc((size_t)N3 * K3 * 2);
  f16* Bt3l = (f16*)palloc((size_t)N3 * K3 * 2);
  f16* ALh = (f16*)palloc((size_t)Bq * KL * 2);
  f16* ALl = (f16*)palloc((size_t)Bq * KL * 2);
  f16* BLh = (f16*)palloc((size_t)NL * KL * 2);
  f16* BLl = (f16*)palloc((size_t)NL * KL * 2);
  float* gates = (float*)palloc((size_t)Bq * NL * 4);
  f16* zAH = (f16*)palloc((size_t)Bq * 576 * 2);
  f16* zAL = (f16*)palloc((size_t)Bq * 576 * 2);
  f16* zBH = (f16*)palloc((size_t)Bq * 576 * 2);
  f16* zBL = (f16*)palloc((size_t)Bq * 576 * 2);
  f16* Btd1h = (f16*)palloc((size_t)ND1 * KD1 * 2);
  f16* Btd1l = (f16*)palloc((size_t)ND1 * KD1 * 2);
  f16* z1h = (f16*)palloc((size_t)Bq * ND1 * 2);
  f16* z1l = (f16*)palloc((size_t)Bq * ND1 * 2);
  f16* Bthh = (f16*)palloc((size_t)8 * 64 * KH * 2);
  f16* Bthl = (f16*)palloc((size_t)8 * 64 * KH * 2);
  float* logitsF = (float*)palloc((size_t)Bq * 64 * 4);
  f16* Btdoh = (f16*)palloc((size_t)NDO * KDO * 2);
  f16* Btdol = (f16*)palloc((size_t)NDO * KDO * 2);
  float* wsLogp = (float*)palloc((size_t)Bq * 4);
  float* wsEnt = (float*)palloc(64);

  // ---- subkeys (host, seed 42 only) ----
  uint32_t k0 = 0u, k1 = 42u;
  uint32_t sk[8][2];
  for (int h = 0; h < 8; ++h) {
    if (kPartitionable) {
      uint32_t a0, a1, b0v, b1v;
      tf2x32(k0, k1, 0u, 0u, a0, a1);
      tf2x32(k0, k1, 0u, 1u, b0v, b1v);
      sk[h][0] = b0v; sk[h][1] = b1v;
      k0 = a0; k1 = a1;
    } else {
      uint32_t a0, a1, b0v, b1v;
      tf2x32(k0, k1, 0u, 2u, a0, a1);
      tf2x32(k0, k1, 1u, 3u, b0v, b1v);
      sk[h][0] = a1; sk[h][1] = b1v;
      k0 = a0; k1 = b0v;
    }
  }
  Ptr8 hws;
  for (int h = 0; h < 8; ++h) hws.p[h] = headW[h];

  dim3 blk(256);
  dim3 tblk(32, 8);

  conv_feats<<<(4096u * 9280u + 255) / 256, blk, 0, stream>>>(actual, object, lastA, ep, A1h, A1l);
  convT_kernel<<<dim3(K1 / 32, N1 / 32), tblk, 0, stream>>>(W1, 9225, 3518, Bt1h, Bt1l, K1);
  convT_kernel<<<dim3(K2 / 32, N2 / 32), tblk, 0, stream>>>(W2, 3518, 1342, Bt2h, Bt2l, K2);

  gemm_split<128, 128><<<dim3(Bq / 128, N1 / 128), blk, 0, stream>>>(
      A1h, A1l, K1, Bt1h, Bt1l, K1, K1, b1, nullptr, N1r, 1, 0, nullptr, x1h, x1l, K2);

  // pool conversions (A1 dead now)
  init_ws<<<(4096u * 63u + 255) / 256, blk, 0, stream>>>(zAH, zAL, zBH, zBL, wsLogp, wsEnt);
  convT_kernel<<<dim3(K3 / 32, N3 / 32), tblk, 0, stream>>>(W3, 1342, 512, Bt3h, Bt3l, K3);
  conv_lstmB<<<(2048u * 1024u) / 256, blk, 0, stream>>>(Wih, Whh, BLh, BLl);
  conv_h0<<<(4096u * 512u) / 256, blk, 0, stream>>>(h0, ALh, ALl);
  convT_kernel<<<dim3(KD1 / 32, ND1 / 32), tblk, 0, stream>>>(dW1, 512, 256, Btd1h, Btd1l, KD1);
  convT_kernel<<<dim3(KDO / 32, NDO / 32), tblk, 0, stream>>>(dWo, 513, 512, Btdoh, Btdol, KDO);
  convT_heads<<<dim3(KH / 32, 2, 8), tblk, 0, stream>>>(hws, Bthh, Bthl);

  gemm_split<128, 128><<<dim3(Bq / 128, N2 / 128), blk, 0, stream>>>(
      x1h, x1l, K2, Bt2h, Bt2l, K2, K2, b2, nullptr, N2r, 1, 0, nullptr, x2h, x2l, K3);
  gemm_split<128, 128><<<dim3(Bq / 128, N3 / 128), blk, 0, stream>>>(
      x2h, x2l, K3, Bt3h, Bt3l, K3, K3, b3, nullptr, N3, 1, 0, nullptr, ALh, ALl, KL);
  gemm_split<128, 128><<<dim3(Bq / 128, NL / 128), blk, 0, stream>>>(
      ALh, ALl, KL, BLh, BLl, KL, KL, bih, bhh, NL, 0, 1, gates, nullptr, nullptr, NL);
  lstm_pointwise<<<(4096u * 512u) / 256, blk, 0, stream>>>(gates, c0, zAH, zAL);

  // decoder (multi-launch; per-head chain)
  for (int h = 0; h < 8; ++h) {
    f16* curH = (h & 1) ? zBH : zAH;
    f16* curL = (h & 1) ? zBL : zAL;
    f16* nxtH = (h & 1) ? zAH : zBH;
    f16* nxtL = (h & 1) ? zAL : zBL;
    // z1 = relu(z @ dW1 + db1)
    gemm_split<64, 64><<<dim3(Bq / 64, ND1 / 64), blk, 0, stream>>>(
        curH, curL, 576, Btd1h, Btd1l, KD1, KD1, db1, nullptr, ND1, 1, 0, nullptr, z1h, z1l, ND1);
    // logits = z1 @ Wk + bk  (N=64, f32 linear out, ld 64)
    gemm_split<64, 64><<<dim3(Bq / 64, 1), blk, 0, stream>>>(
        z1h, z1l, ND1, Bthh + (size_t)h * 64 * KH, Bthl + (size_t)h * 64 * KH, KH, KH,
        headb[h], nullptr, 64, 0, 1, logitsF, nullptr, nullptr, 64);
    // sample + entropy + logp; writes act into cur zcat col 512
    sample_head<<<Bq / 4, blk, 0, stream>>>(logitsF, sk[h][0], sk[h][1], h, kPartitionable,
                                            (float*)d_out, curH, curL, wsLogp, wsEnt);
    // z = relu([z|act] @ dWo + dbo) -> next zcat cols 0..511
    gemm_split<64, 64><<<dim3(Bq / 64, NDO / 64), blk, 0, stream>>>(
        curH, curL, 576, Btdoh, Btdol, KDO, KDO, dbo, nullptr, NDO, 1, 0, nullptr, nxtH, nxtL, 576);
  }
  finalize_out<<<(4097 + 255) / 256, blk, 0, stream>>>(wsEnt, wsLogp, (float*)d_out);
}